// Round 19
// baseline (115.697 us; speedup 1.0000x reference)
//
#include <hip/hip_runtime.h>
#include <math.h>
#include <stdint.h>

#define B 64
#define SDIM 2048
#define FEAT 128
#define P 4
#define PK 8196
#define NCLS 7
#define PER 1000
#define NDATA 100000
#define EPSC 1e-7f
#define M_PN 0.08192f   /* (PK-P)/NDATA = 8192/100000 */
#define JCHUNKS 50
#define CS (PER / JCHUNKS)   /* 20 rows per block */

#define DTBF ((size_t)B * NDATA / 2)  /* float-units of one bf16 DT table */
#define KSPLIT 4
#define KSEG 2049            /* 4*2049 = 8196 = PK */
#define KS1 8                /* K-split for gemm_partial */
#define TPW 4                /* tiles (16 rows) per wave */
#define WVS 2                /* waves per block (32 KB LDS -> 4-5 blocks/CU) */
#define ROWS_BLK (WVS * TPW * 16)   /* 128 rows per block */

/* fallback (R7) dots config */
#define TILE 16
#define WCHUNK 512
#define NT (WCHUNK / TILE)

#define GLL16(gp, lp) \
    __builtin_amdgcn_global_load_lds( \
        (__attribute__((address_space(1))) void*)(uintptr_t)(gp), \
        (__attribute__((address_space(3))) void*)(lp), 16, 0, 0)

typedef __attribute__((ext_vector_type(8))) short bf16x8;
typedef __attribute__((ext_vector_type(4))) float f32x4;

static __device__ __forceinline__ short f2bf(float x)
{
    union { float f; uint32_t u; } v; v.f = x;
    const uint32_t r = (v.u + 0x7fffu + ((v.u >> 16) & 1u)) >> 16;
    return (short)r;
}
static __device__ __forceinline__ float bf2f(unsigned short u)
{
    union { uint32_t u; float f; } v; v.u = ((uint32_t)u) << 16;
    return v.f;
}

// ---- K1a: fbp[ks][z][row][d] = partial dot over one K-chunk (no atomics) ----
__global__ void gemm_partial_kernel(const float* __restrict__ f_s,
                                    const float* __restrict__ f_t,
                                    const float* __restrict__ W_s,
                                    const float* __restrict__ W_t,
                                    float* __restrict__ fbp)  // [KS1][2][B][FEAT]
{
    const int row = blockIdx.x;
    const int z   = blockIdx.y;
    const int ks  = blockIdx.z;        // 0..KS1-1
    const float* f = z == 0 ? f_s : f_t;
    const float* W = z == 0 ? W_s : W_t;

    const int t  = threadIdx.x;        // 0..255
    const int d  = t & 127;
    const int kh = t >> 7;             // 0/1

    __shared__ float frow[SDIM / KS1]; // 256
    frow[t] = f[row * SDIM + ks * (SDIM / KS1) + t];
    __syncthreads();

    float acc = 0.0f;
    const int kb = ks * (SDIM / KS1) + kh * 128;
    #pragma unroll 8
    for (int k = 0; k < 128; ++k)
        acc = fmaf(frow[kh * 128 + k], W[(kb + k) * FEAT + d], acc);

    __shared__ float part[2][128];
    part[kh][d] = acc;
    __syncthreads();
    if (t < 128)
        fbp[(((size_t)ks * 2 + z) * B + row) * FEAT + t] = part[0][t] + part[1][t];
}

// ---- K1b: sum ks-slices + bias + l2norm; ALSO computes upd (fused) ----
__global__ void norm_finish_kernel(const float* __restrict__ fbp,
                                   const float* __restrict__ b_s,
                                   const float* __restrict__ b_t,
                                   const int*   __restrict__ idx,
                                   const float* __restrict__ mem_s,
                                   const float* __restrict__ mem_t,
                                   float* __restrict__ out_fs,
                                   float* __restrict__ out_ft,
                                   unsigned short* __restrict__ fsb,
                                   unsigned short* __restrict__ ftb,
                                   float* __restrict__ upd)   // [2][B][FEAT]
{
    const int row = blockIdx.x;
    const int z   = blockIdx.y;
    const int d   = threadIdx.x;       // 128
    const float* bias = z == 0 ? b_s : b_t;
    float* out = z == 0 ? out_fs : out_ft;
    unsigned short* fbx = z == 0 ? fsb : ftb;

    float a = bias[d];
    #pragma unroll
    for (int ks = 0; ks < KS1; ++ks)
        a += fbp[(((size_t)ks * 2 + z) * B + row) * FEAT + d];

    __shared__ float red[128];
    red[d] = a * a;
    __syncthreads();
    for (int s = 64; s > 0; s >>= 1) {
        if (d < s) red[d] += red[d + s];
        __syncthreads();
    }
    const float v = a * (1.0f / sqrtf(red[0]));
    out[row * FEAT + d] = v;
    fbx[row * FEAT + d] = (unsigned short)f2bf(v);
    __syncthreads();                   // red reuse

    const float* mem = z == 0 ? mem_s : mem_t;   // NOT cross-paired here
    const int i = idx[row];
    const float u = mem[(size_t)i * FEAT + d] * 0.5f + v * 0.5f;
    red[d] = u * u;
    __syncthreads();
    for (int s = 64; s > 0; s >>= 1) {
        if (d < s) red[d] += red[d + s];
        __syncthreads();
    }
    upd[((size_t)z * B + row) * FEAT + d] = u * (1.0f / sqrtf(red[0]));
}

// ---- K2a v8: DT(bf16) = mem . f via bf16 MFMA; 2 waves / 32 KB LDS ----
// Same wave-private double-buffered pipeline, but 2-wave blocks => 32 KB
// LDS => 4-5 blocks/CU = 8-10 waves/CU (every prior variant was capped
// at ~4 waves/CU by 64 KB blocks or by serial per-z launches).
#define MFMA4(av, kc, a0, a1, a2, a3) do { \
    a0 = __builtin_amdgcn_mfma_f32_16x16x32_bf16(av, bv[kc][0], a0, 0, 0, 0); \
    a1 = __builtin_amdgcn_mfma_f32_16x16x32_bf16(av, bv[kc][1], a1, 0, 0, 0); \
    a2 = __builtin_amdgcn_mfma_f32_16x16x32_bf16(av, bv[kc][2], a2, 0, 0, 0); \
    a3 = __builtin_amdgcn_mfma_f32_16x16x32_bf16(av, bv[kc][3], a3, 0, 0, 0); \
    } while (0)

__global__ __launch_bounds__(WVS * 64, 2)
void dgemm8_kernel(const unsigned short* __restrict__ fsb,
                   const unsigned short* __restrict__ ftb,
                   const float* __restrict__ mem_s,
                   const float* __restrict__ mem_t,
                   short* __restrict__ DT0,      // bf16 [B][NDATA]
                   short* __restrict__ DT1)
{
    const int z = blockIdx.y;
    const unsigned short* fWb = z == 0 ? fsb : ftb;
    const float* mem          = z == 0 ? mem_t : mem_s;   // cross pairing
    short* DT                 = z == 0 ? DT0 : DT1;

    const int tid = threadIdx.x;
    const int w   = tid >> 6;          // wave 0..WVS-1
    const int l   = tid & 63;
    const int ln  = l & 15;
    const int ko  = l >> 4;            // 0..3
    const int xk  = ln & 7;            // read-side swizzle key
    const int wrowbase = blockIdx.x * ROWS_BLK + w * (TPW * 16);

    __shared__ __align__(16) float rows[WVS][2][16 * FEAT];  // 2 x 2 x 8 KB

    bf16x8 bv[4][4];
    #pragma unroll
    for (int kc = 0; kc < 4; ++kc)
        #pragma unroll
        for (int nt = 0; nt < 4; ++nt)
            bv[kc][nt] = *(const bf16x8*)(fWb + (nt * 16 + ln) * FEAT + kc * 32 + ko * 8);

#define STG(tt, bf) do { \
    _Pragma("unroll") \
    for (int p_ = 0; p_ < 8; ++p_) { \
        const int r_ = 2 * p_ + (l >> 5); \
        int gr_ = wrowbase + (tt) * 16 + r_; \
        if (gr_ >= NDATA) gr_ = NDATA - 1; \
        const float* g_ = mem + (size_t)gr_ * FEAT + (((l & 31) ^ (r_ & 7)) << 2); \
        GLL16(g_, &rows[w][bf][p_ * 256]); \
    } } while (0)

#define STORE_BF(cc, nt) do { \
    short4 s_; \
    s_.x = f2bf((cc).x); s_.y = f2bf((cc).y); \
    s_.z = f2bf((cc).z); s_.w = f2bf((cc).w); \
    *(short4*)(DT + (size_t)((nt) * 16 + ln) * NDATA + growb) = s_; \
    } while (0)

    STG(0, 0);
    int cur = 0;
    #pragma unroll
    for (int t = 0; t < TPW; ++t) {
        if (t + 1 < TPW) {
            STG(t + 1, cur ^ 1);
            if (t == 0) {
                // queue: L0(8), L1(8); want L0 done
                asm volatile("s_waitcnt vmcnt(8)" ::: "memory");
            } else {
                // queue: L(t)(8), ST(t-1)(4), L(t+1)(8); want L(t) done
                asm volatile("s_waitcnt vmcnt(12)" ::: "memory");
            }
        } else {
            // queue: L(t)(8), ST(t-1)(4); want L(t) done -> 4 left
            asm volatile("s_waitcnt vmcnt(4)" ::: "memory");
        }
        __builtin_amdgcn_sched_barrier(0);

        const float* rb = &rows[w][cur][ln * FEAT];
        f32x4 c0 = (f32x4){0.f,0.f,0.f,0.f};
        f32x4 c1 = (f32x4){0.f,0.f,0.f,0.f};
        f32x4 c2 = (f32x4){0.f,0.f,0.f,0.f};
        f32x4 c3 = (f32x4){0.f,0.f,0.f,0.f};
        #pragma unroll
        for (int kc = 0; kc < 4; ++kc) {
            const int g0 = kc * 8 + ko * 2;
            const float4 lo = *(const float4*)(rb + (((g0 + 0) ^ xk) << 2));
            const float4 hi = *(const float4*)(rb + (((g0 + 1) ^ xk) << 2));
            const bf16x8 av = (bf16x8){ f2bf(lo.x), f2bf(lo.y), f2bf(lo.z), f2bf(lo.w),
                                        f2bf(hi.x), f2bf(hi.y), f2bf(hi.z), f2bf(hi.w) };
            MFMA4(av, kc, c0, c1, c2, c3);
        }

        const int growb = wrowbase + t * 16 + ko * 4;
        if (growb < NDATA) {                      // NDATA%4==0 -> full x4 ok
            STORE_BF(c0, 0);
            STORE_BF(c1, 1);
            STORE_BF(c2, 2);
            STORE_BF(c3, 3);
        }
        cur ^= 1;
    }
#undef STG
#undef STORE_BF
}

// ---- K2b: out_raw + Ssum from bf16 DT ----
__global__ void gather2_kernel(const int* __restrict__ contrast_idx,
                               const unsigned short* __restrict__ DT0,
                               const unsigned short* __restrict__ DT1,
                               float* __restrict__ out_raw,  // [2][B*PK]
                               float* __restrict__ Ssum)     // [2]
{
    const int z   = blockIdx.z;
    const int b   = blockIdx.y;
    const int ks  = blockIdx.x;
    const int tid = threadIdx.x;
    const int k0  = ks * KSEG;
    const int kend = min(k0 + KSEG, PK);
    const float inv_t = 1.0f / 0.07f;
    const unsigned short* dtb = (z == 0 ? DT0 : DT1) + (size_t)b * NDATA;
    float* orz = out_raw + (size_t)z * (B * PK);
    float lsum = 0.0f;
    #pragma unroll 4
    for (int k = k0 + tid; k < kend; k += 256) {
        const int ci = contrast_idx[(size_t)b * PK + k];
        const float v = expf(bf2f(dtb[ci]) * inv_t);
        orz[(size_t)b * PK + k] = v;
        lsum += v;
    }
    __shared__ float red[256];
    red[tid] = lsum;
    __syncthreads();
    for (int s = 128; s > 0; s >>= 1) {
        if (tid < s) red[tid] += red[tid + s];
        __syncthreads();
    }
    if (tid == 0) atomicAdd(&Ssum[z], red[0]);
}

// ---- K3: weighted loss from out_raw ----
__global__ void ccd_loss_kernel(const float* __restrict__ out_raw,
                                const float* __restrict__ Ssum,
                                float* __restrict__ acc)
{
    const int z = blockIdx.y;
    const float S = Ssum[z];
    const float c = ((float)(B * PK)) / (S * (float)NDATA);

    const int total = B * PK;
    float contrib = 0.0f;
    for (int i = blockIdx.x * blockDim.x + threadIdx.x; i < total;
         i += gridDim.x * blockDim.x) {
        const float v = out_raw[(size_t)z * total + i] * c;
        const int k = i % PK;
        if (k < P) {
            contrib += logf(v / (v + M_PN + EPSC));
        } else {
            contrib += (float)P * logf(M_PN / (v + M_PN + EPSC));
        }
    }
    __shared__ float red[256];
    red[threadIdx.x] = contrib;
    __syncthreads();
    for (int s = 128; s > 0; s >>= 1) {
        if (threadIdx.x < s) red[threadIdx.x] += red[threadIdx.x + s];
        __syncthreads();
    }
    if (threadIdx.x == 0) atomicAdd(&acc[z], red[0]);
}

// ---------------- fallback K1 (R7): f = l2norm(f @ W + b) ----------------
__global__ void gemm_norm_kernel(const float* __restrict__ f_s,
                                 const float* __restrict__ f_t,
                                 const float* __restrict__ W_s,
                                 const float* __restrict__ b_s,
                                 const float* __restrict__ W_t,
                                 const float* __restrict__ b_t,
                                 float* __restrict__ out_fs,
                                 float* __restrict__ out_ft)
{
    const int row = blockIdx.x;
    const int z   = blockIdx.y;
    const float* f    = z == 0 ? f_s : f_t;
    const float* W    = z == 0 ? W_s : W_t;
    const float* bias = z == 0 ? b_s : b_t;
    float* out        = z == 0 ? out_fs : out_ft;

    __shared__ __align__(16) float frow[SDIM];
    const int t  = threadIdx.x;
    const int d  = t & 127;
    const int kh = t >> 7;
    for (int k = t; k < SDIM; k += 256) frow[k] = f[row * SDIM + k];
    __syncthreads();

    float acc = 0.0f;
    const int k0 = kh * (SDIM / 2);
    for (int k = k0; k < k0 + SDIM / 2; ++k)
        acc = fmaf(frow[k], W[k * FEAT + d], acc);

    __shared__ float part[2][128];
    part[kh][d] = acc;
    __syncthreads();
    const float a = part[0][d] + part[1][d] + bias[d];

    __shared__ float red[256];
    red[t] = (t < 128) ? a * a : 0.0f;
    __syncthreads();
    for (int s = 128; s > 0; s >>= 1) {
        if (t < s) red[t] += red[t + s];
        __syncthreads();
    }
    if (t < 128) out[row * FEAT + t] = a * (1.0f / sqrtf(red[0]));
}

// ---- FALLBACK dots (R7) ----
__global__ __launch_bounds__(64)
void dots_kernel(const float* __restrict__ fsn,
                 const float* __restrict__ ftn,
                 const int*   __restrict__ contrast_idx,
                 const float* __restrict__ mem_s,
                 const float* __restrict__ mem_t,
                 float* __restrict__ out_raw,
                 float* __restrict__ Ssum)
{
    const int z = blockIdx.z;
    const int b = blockIdx.y;
    const int l = threadIdx.x;
    const int kchunk = blockIdx.x * WCHUNK;

    const float* f   = (z == 0 ? fsn : ftn) + b * FEAT;
    const float* mem = (z == 0 ? mem_t : mem_s);

    __shared__ __align__(16) float rows[2][TILE * FEAT];
    __shared__ __align__(16) float fl[FEAT];
    __shared__ int cis[WCHUNK];

    fl[l]      = f[l];
    fl[l + 64] = f[l + 64];
    for (int i = l; i < WCHUNK; i += 64) {
        const int k = kchunk + i;
        cis[i] = contrast_idx[(size_t)b * PK + (k < PK ? k : PK - 1)];
    }
    __syncthreads();

    const int q   = l >> 4;
    const int r_c = l & 15;
    const int xk  = r_c & 7;
    const int rh  = l >> 5;
    const int sl  = l & 31;

    const float4* fg = (const float4*)fl;
    const float4 f0 = fg[q * 8 + 0], f1 = fg[q * 8 + 1];
    const float4 f2 = fg[q * 8 + 2], f3 = fg[q * 8 + 3];
    const float4 f4 = fg[q * 8 + 4], f5 = fg[q * 8 + 5];
    const float4 f6 = fg[q * 8 + 6], f7 = fg[q * 8 + 7];

    const float inv_t = 1.0f / 0.07f;
    const size_t obase = (size_t)z * (B * PK) + (size_t)b * PK;
    float lsum = 0.0f;

#define STAGE(tt, bf) do { \
    _Pragma("unroll") \
    for (int p_ = 0; p_ < 8; ++p_) { \
        const int rr_ = 2 * p_ + rh; \
        const int ci_ = cis[(tt) * TILE + rr_]; \
        const float* g_ = mem + (size_t)ci_ * FEAT + ((sl ^ (rr_ & 7)) << 2); \
        GLL16(g_, &rows[bf][p_ * 256]); \
    } } while (0)

    STAGE(0, 0);
    int cur = 0;
    for (int t = 0; t < NT; ++t) {
        if (t + 1 < NT) {
            STAGE(t + 1, cur ^ 1);
            asm volatile("s_waitcnt vmcnt(8)" ::: "memory");
        } else {
            asm volatile("s_waitcnt vmcnt(0)" ::: "memory");
        }
        __builtin_amdgcn_sched_barrier(0);

        const float* rbase = &rows[cur][r_c * FEAT];
        float dot;
        {
            const float4 m0 = *(const float4*)(rbase + (((q * 8 + 0) ^ xk) << 2));
            const float4 m1 = *(const float4*)(rbase + (((q * 8 + 1) ^ xk) << 2));
            const float4 m2 = *(const float4*)(rbase + (((q * 8 + 2) ^ xk) << 2));
            const float4 m3 = *(const float4*)(rbase + (((q * 8 + 3) ^ xk) << 2));
            const float4 m4 = *(const float4*)(rbase + (((q * 8 + 4) ^ xk) << 2));
            const float4 m5 = *(const float4*)(rbase + (((q * 8 + 5) ^ xk) << 2));
            const float4 m6 = *(const float4*)(rbase + (((q * 8 + 6) ^ xk) << 2));
            const float4 m7 = *(const float4*)(rbase + (((q * 8 + 7) ^ xk) << 2));
            dot = m0.x * f0.x;
            dot = fmaf(m0.y, f0.y, dot); dot = fmaf(m0.z, f0.z, dot); dot = fmaf(m0.w, f0.w, dot);
            dot = fmaf(m1.x, f1.x, dot); dot = fmaf(m1.y, f1.y, dot); dot = fmaf(m1.z, f1.z, dot); dot = fmaf(m1.w, f1.w, dot);
            dot = fmaf(m2.x, f2.x, dot); dot = fmaf(m2.y, f2.y, dot); dot = fmaf(m2.z, f2.z, dot); dot = fmaf(m2.w, f2.w, dot);
            dot = fmaf(m3.x, f3.x, dot); dot = fmaf(m3.y, f3.y, dot); dot = fmaf(m3.z, f3.z, dot); dot = fmaf(m3.w, f3.w, dot);
            dot = fmaf(m4.x, f4.x, dot); dot = fmaf(m4.y, f4.y, dot); dot = fmaf(m4.z, f4.z, dot); dot = fmaf(m4.w, f4.w, dot);
            dot = fmaf(m5.x, f5.x, dot); dot = fmaf(m5.y, f5.y, dot); dot = fmaf(m5.z, f5.z, dot); dot = fmaf(m5.w, f5.w, dot);
            dot = fmaf(m6.x, f6.x, dot); dot = fmaf(m6.y, f6.y, dot); dot = fmaf(m6.z, f6.z, dot); dot = fmaf(m6.w, f6.w, dot);
            dot = fmaf(m7.x, f7.x, dot); dot = fmaf(m7.y, f7.y, dot); dot = fmaf(m7.z, f7.z, dot); dot = fmaf(m7.w, f7.w, dot);
        }
        dot += __shfl_xor(dot, 16);
        dot += __shfl_xor(dot, 32);

        const int krow = kchunk + t * TILE + r_c;
        if (q == 0 && krow < PK) {
            const float val = expf(dot * inv_t);
            out_raw[obase + krow] = val;
            lsum += val;
        }
        cur ^= 1;
    }
#undef STAGE

    lsum += __shfl_xor(lsum, 8);
    lsum += __shfl_xor(lsum, 4);
    lsum += __shfl_xor(lsum, 2);
    lsum += __shfl_xor(lsum, 1);
    if (l == 0) atomicAdd(&Ssum[z], lsum);
}

// ---- fallback-only standalone upd ----
__global__ void upd_kernel(const float* __restrict__ fsn,
                           const float* __restrict__ ftn,
                           const int*   __restrict__ idx,
                           const float* __restrict__ mem_s,
                           const float* __restrict__ mem_t,
                           float* __restrict__ upd)
{
    const int z = blockIdx.y;
    const int b = blockIdx.x;
    const int d = threadIdx.x;
    const float* mem = z == 0 ? mem_s : mem_t;
    const float* f   = z == 0 ? fsn : ftn;
    const int i = idx[b];
    const float v = mem[(size_t)i * FEAT + d] * 0.5f + f[b * FEAT + d] * 0.5f;
    __shared__ float red[128];
    red[d] = v * v;
    __syncthreads();
    for (int s = 64; s > 0; s >>= 1) {
        if (d < s) red[d] += red[d + s];
        __syncthreads();
    }
    upd[(size_t)z * (B * FEAT) + b * FEAT + d] = v * (1.0f / sqrtf(red[0]));
}

// ---- K5: anchors partial with INLINE remap ----
__global__ void anchors_partial2_kernel(const int* __restrict__ class_index,
                                        const int* __restrict__ idx,
                                        const float* __restrict__ mem_s,
                                        const float* __restrict__ mem_t,
                                        const float* __restrict__ upd,
                                        float* __restrict__ partial)
{
    const int z     = blockIdx.z;
    const int c     = blockIdx.y;
    const int chunk = blockIdx.x;
    const int d     = threadIdx.x;     // 128
    const float* mem = z == 0 ? mem_s : mem_t;
    const float* u   = upd + (size_t)z * (B * FEAT);

    __shared__ int lidx[B];
    __shared__ int cis[CS];
    __shared__ int rbs[CS];
    if (d < B) lidx[d] = idx[d];
    __syncthreads();
    if (d < CS) {
        const int e = c * PER + chunk * CS + d;
        const int ci = class_index[e];
        int rb = -1;
        for (int b = B - 1; b >= 0; --b) {
            if (lidx[b] == ci) { rb = b; break; }
        }
        cis[d] = ci;
        rbs[d] = rb;
    }
    __syncthreads();

    float acc = 0.0f;
    #pragma unroll 4
    for (int j = 0; j < CS; ++j) {
        const int ci = cis[j];
        const int rb = rbs[j];
        const float* row = (rb >= 0) ? (u + rb * FEAT) : (mem + (size_t)ci * FEAT);
        const float v = row[d];
        acc += v > 0.0f ? v : 0.0f;
    }
    atomicAdd(&partial[(size_t)z * (NCLS * FEAT) + c * FEAT + d], acc);
}

// ---- K6 v2: anchors-finish + relation loss + final assembly (fused) ----
__global__ void final2_kernel(const float* __restrict__ fsn,
                              const float* __restrict__ ftn,
                              const float* __restrict__ partial,  // [2][NCLS][FEAT]
                              const float* __restrict__ acc,
                              float* __restrict__ d_out)
{
    __shared__ float an[2 * NCLS * FEAT];
    __shared__ float red[128];
    const int tid = threadIdx.x;            // 128

    for (int zc = 0; zc < 2 * NCLS; ++zc) {
        const float mv = partial[(size_t)zc * FEAT + tid] * (1.0f / (float)PER);
        red[tid] = mv * mv;
        __syncthreads();
        for (int s = 64; s > 0; s >>= 1) {
            if (tid < s) red[tid] += red[tid + s];
            __syncthreads();
        }
        an[zc * FEAT + tid] = mv * (1.0f / sqrtf(red[0]));
        __syncthreads();
    }

    float contrib = 0.0f;
    if (tid < 64) {
        const int b = tid;
        const float* sa = an;
        const float* ta = an + NCLS * FEAT;
        float srel[NCLS], trel[NCLS];
        for (int j = 0; j < NCLS; ++j) { srel[j] = 0.0f; trel[j] = 0.0f; }
        for (int d = 0; d < FEAT; ++d) {
            const float fs = fsn[b * FEAT + d];
            const float ft = ftn[b * FEAT + d];
            #pragma unroll
            for (int j = 0; j < NCLS; ++j) {
                srel[j] = fmaf(fs, sa[j * FEAT + d], srel[j]);
                trel[j] = fmaf(ft, ta[j * FEAT + d], trel[j]);
            }
        }
        const float inv_t = 1.0f / 0.07f;
        float smax = -1e30f, tmax = -1e30f;
        for (int j = 0; j < NCLS; ++j) {
            srel[j] *= inv_t; trel[j] *= inv_t;
            smax = fmaxf(smax, srel[j]);
            tmax = fmaxf(tmax, trel[j]);
        }
        float ssum = 0.0f, tsum = 0.0f;
        float texp[NCLS];
        for (int j = 0; j < NCLS; ++j) {
            ssum += expf(srel[j] - smax);
            texp[j] = expf(trel[j] - tmax);
            tsum += texp[j];
        }
        const float lse_s = logf(ssum);
        for (int j = 0; j < NCLS; ++j) {
            const float tgt = texp[j] / tsum;
            const float log_in = srel[j] - smax - lse_s;
            contrib += tgt * (logf(tgt + 1e-30f) - log_in);
        }
        for (int off = 32; off > 0; off >>= 1) contrib += __shfl_down(contrib, off);
        if (tid == 0) {
            d_out[1] = contrib / (float)B;
            d_out[0] = -(acc[0] + acc[1]) / (float)(B * P);
        }
    }
}

extern "C" void kernel_launch(void* const* d_in, const int* in_sizes, int n_in,
                              void* d_out_v, int out_size, void* d_ws, size_t ws_size,
                              hipStream_t stream)
{
    const float* f_s = (const float*)d_in[0];
    const float* f_t = (const float*)d_in[1];
    const int*   idx = (const int*)d_in[2];
    const int*   class_index = (const int*)d_in[4];
    const int*   contrast_idx = (const int*)d_in[6];
    const float* W_s = (const float*)d_in[7];
    const float* b_s = (const float*)d_in[8];
    const float* W_t = (const float*)d_in[9];
    const float* b_t = (const float*)d_in[10];
    const float* mem_s = (const float*)d_in[11];
    const float* mem_t = (const float*)d_in[12];

    float* out    = (float*)d_out_v;
    float* out_fs = out + 2;
    float* out_ft = out + 2 + B * FEAT;

    float* ws = (float*)d_ws;
    const size_t fl = ws_size / sizeof(float);
    const size_t REST = 2 * (size_t)B * PK   /* out_raw */
                      + (size_t)B * FEAT     /* fsb+ftb (bf16) */
                      + (size_t)KS1 * 2 * B * FEAT  /* fbp */
                      + 2 * B * FEAT         /* upd      */
                      + 2 * NCLS * FEAT      /* partial  */
                      + 64;
    const bool fit = fl >= 2 * DTBF + REST;  /* both bf16 tables */

    if (fit) {
        // ---------- bf16 D-table path, single dgemm launch ----------
        short* DT0 = (short*)ws;
        short* DT1 = (short*)(ws + DTBF);
        float* p   = ws + 2 * DTBF;
        float* out_raw = p;            p += 2 * (size_t)B * PK;
        unsigned short* fsb = (unsigned short*)p;  p += B * FEAT / 2;
        unsigned short* ftb = (unsigned short*)p;  p += B * FEAT / 2;
        float* fbp     = p;            p += (size_t)KS1 * 2 * B * FEAT;
        float* upd     = p;            p += 2 * B * FEAT;
        float* partial = p;            p += 2 * NCLS * FEAT;
        float* Ssum    = p;            p += 2;
        float* acc     = p;            p += 2;

        hipMemsetAsync(partial, 0, (2 * NCLS * FEAT + 4) * sizeof(float), stream);

        dim3 g1a(B, 2, KS1);
        gemm_partial_kernel<<<g1a, 256, 0, stream>>>(f_s, f_t, W_s, W_t, fbp);
        dim3 g1b(B, 2);
        norm_finish_kernel<<<g1b, 128, 0, stream>>>(fbp, b_s, b_t, idx,
                                                    mem_s, mem_t,
                                                    out_fs, out_ft, fsb, ftb, upd);

        const int gblocks = (NDATA + ROWS_BLK - 1) / ROWS_BLK;   // 782
        dim3 gd(gblocks, 2);
        dgemm8_kernel<<<gd, WVS * 64, 0, stream>>>(fsb, ftb, mem_s, mem_t,
                                                   DT0, DT1);
        dim3 gg(KSPLIT, B, 2);
        gather2_kernel<<<gg, 256, 0, stream>>>(contrast_idx,
                                               (const unsigned short*)DT0,
                                               (const unsigned short*)DT1,
                                               out_raw, Ssum);

        dim3 g3(256, 2);
        ccd_loss_kernel<<<g3, 256, 0, stream>>>(out_raw, Ssum, acc);
        dim3 g5a(JCHUNKS, NCLS, 2);
        anchors_partial2_kernel<<<g5a, 128, 0, stream>>>(class_index, idx,
                                                         mem_s, mem_t, upd, partial);
        final2_kernel<<<1, 128, 0, stream>>>(out_fs, out_ft, partial, acc, out);
    } else {
        // ---------- fallback: R7-style path ----------
        float* out_raw = ws;
        float* upd     = out_raw + 2 * (B * PK);
        float* partial = upd + 2 * (B * FEAT);
        float* Ssum    = partial + 2 * (NCLS * FEAT);
        float* acc     = Ssum + 2;

        hipMemsetAsync(partial, 0, (2 * NCLS * FEAT + 4) * sizeof(float), stream);

        dim3 g1(B, 2);
        gemm_norm_kernel<<<g1, 256, 0, stream>>>(f_s, f_t, W_s, b_s, W_t, b_t,
                                                 out_fs, out_ft);
        dim3 g2((PK + WCHUNK - 1) / WCHUNK, B, 2);
        dots_kernel<<<g2, 64, 0, stream>>>(out_fs, out_ft, contrast_idx,
                                           mem_s, mem_t, out_raw, Ssum);
        dim3 g3(256, 2);
        ccd_loss_kernel<<<g3, 256, 0, stream>>>(out_raw, Ssum, acc);
        dim3 g4(B, 2);
        upd_kernel<<<g4, 128, 0, stream>>>(out_fs, out_ft, idx, mem_s, mem_t, upd);
        dim3 g5a(JCHUNKS, NCLS, 2);
        anchors_partial2_kernel<<<g5a, 128, 0, stream>>>(class_index, idx,
                                                         mem_s, mem_t, upd, partial);
        final2_kernel<<<1, 128, 0, stream>>>(out_fs, out_ft, partial, acc, out);
    }
}

// Round 20
// 113.677 us; speedup vs baseline: 1.0178x; 1.0178x over previous
//
#include <hip/hip_runtime.h>
#include <math.h>
#include <stdint.h>

#define B 64
#define SDIM 2048
#define FEAT 128
#define P 4
#define PK 8196
#define NCLS 7
#define PER 1000
#define NDATA 100000
#define EPSC 1e-7f
#define M_PN 0.08192f   /* (PK-P)/NDATA = 8192/100000 */
#define JCHUNKS 50
#define CS (PER / JCHUNKS)   /* 20 rows per block */

#define DTBF ((size_t)B * NDATA / 2)  /* float-units of one bf16 DT table */
#define KSPLIT 4
#define KSEG 2049            /* 4*2049 = 8196 = PK */
#define KS1 8                /* K-split for gemm_partial */
#define TPW 4                /* tiles (16 rows) per wave */
#define WVS 2                /* waves per block */
#define ROWS_BLK (WVS * TPW * 16)   /* 128 rows per block */

/* fallback (R7) dots config */
#define TILE 16
#define WCHUNK 512
#define NT (WCHUNK / TILE)

#define GLL16(gp, lp) \
    __builtin_amdgcn_global_load_lds( \
        (__attribute__((address_space(1))) void*)(uintptr_t)(gp), \
        (__attribute__((address_space(3))) void*)(lp), 16, 0, 0)

typedef __attribute__((ext_vector_type(8))) short bf16x8;
typedef __attribute__((ext_vector_type(4))) float f32x4;

static __device__ __forceinline__ short f2bf(float x)
{
    union { float f; uint32_t u; } v; v.f = x;
    const uint32_t r = (v.u + 0x7fffu + ((v.u >> 16) & 1u)) >> 16;
    return (short)r;
}
static __device__ __forceinline__ float bf2f(unsigned short u)
{
    union { uint32_t u; float f; } v; v.u = ((uint32_t)u) << 16;
    return v.f;
}

// ---- K1a: fbp[ks][z][row][d] = partial dot over one K-chunk (no atomics) ----
__global__ void gemm_partial_kernel(const float* __restrict__ f_s,
                                    const float* __restrict__ f_t,
                                    const float* __restrict__ W_s,
                                    const float* __restrict__ W_t,
                                    float* __restrict__ fbp)  // [KS1][2][B][FEAT]
{
    const int row = blockIdx.x;
    const int z   = blockIdx.y;
    const int ks  = blockIdx.z;        // 0..KS1-1
    const float* f = z == 0 ? f_s : f_t;
    const float* W = z == 0 ? W_s : W_t;

    const int t  = threadIdx.x;        // 0..255
    const int d  = t & 127;
    const int kh = t >> 7;             // 0/1

    __shared__ float frow[SDIM / KS1]; // 256
    frow[t] = f[row * SDIM + ks * (SDIM / KS1) + t];
    __syncthreads();

    float acc = 0.0f;
    const int kb = ks * (SDIM / KS1) + kh * 128;
    #pragma unroll 8
    for (int k = 0; k < 128; ++k)
        acc = fmaf(frow[kh * 128 + k], W[(kb + k) * FEAT + d], acc);

    __shared__ float part[2][128];
    part[kh][d] = acc;
    __syncthreads();
    if (t < 128)
        fbp[(((size_t)ks * 2 + z) * B + row) * FEAT + t] = part[0][t] + part[1][t];
}

// ---- K1b: sum ks-slices + bias + l2norm; ALSO computes upd (fused) ----
__global__ void norm_finish_kernel(const float* __restrict__ fbp,
                                   const float* __restrict__ b_s,
                                   const float* __restrict__ b_t,
                                   const int*   __restrict__ idx,
                                   const float* __restrict__ mem_s,
                                   const float* __restrict__ mem_t,
                                   float* __restrict__ out_fs,
                                   float* __restrict__ out_ft,
                                   unsigned short* __restrict__ fsb,
                                   unsigned short* __restrict__ ftb,
                                   float* __restrict__ upd)   // [2][B][FEAT]
{
    const int row = blockIdx.x;
    const int z   = blockIdx.y;
    const int d   = threadIdx.x;       // 128
    const float* bias = z == 0 ? b_s : b_t;
    float* out = z == 0 ? out_fs : out_ft;
    unsigned short* fbx = z == 0 ? fsb : ftb;

    float a = bias[d];
    #pragma unroll
    for (int ks = 0; ks < KS1; ++ks)
        a += fbp[(((size_t)ks * 2 + z) * B + row) * FEAT + d];

    __shared__ float red[128];
    red[d] = a * a;
    __syncthreads();
    for (int s = 64; s > 0; s >>= 1) {
        if (d < s) red[d] += red[d + s];
        __syncthreads();
    }
    const float v = a * (1.0f / sqrtf(red[0]));
    out[row * FEAT + d] = v;
    fbx[row * FEAT + d] = (unsigned short)f2bf(v);
    __syncthreads();                   // red reuse

    const float* mem = z == 0 ? mem_s : mem_t;   // NOT cross-paired here
    const int i = idx[row];
    const float u = mem[(size_t)i * FEAT + d] * 0.5f + v * 0.5f;
    red[d] = u * u;
    __syncthreads();
    for (int s = 64; s > 0; s >>= 1) {
        if (d < s) red[d] += red[d + s];
        __syncthreads();
    }
    upd[((size_t)z * B + row) * FEAT + d] = u * (1.0f / sqrtf(red[0]));
}

// ---- K2a v9: DT(bf16) = mem . f via bf16 MFMA; DEPTH-2 prefetch ----
// 2 waves/block, 3 wave-private 8 KB buffers (48 KB/block -> 3 blocks/CU).
// Per wave, TWO tiles' loads (16 KB) stay in flight across each compute
// phase (every prior variant was depth-1 = 8 KB).
// In-order issue: L0,L1 | S0,L2 | S1,L3 | S2 | S3; waits t0=vmcnt(8),
// t1=t2=vmcnt(12), t3=vmcnt(4) -- stores never force-drained in-loop.
#define MFMA4(av, kc, a0, a1, a2, a3) do { \
    a0 = __builtin_amdgcn_mfma_f32_16x16x32_bf16(av, bv[kc][0], a0, 0, 0, 0); \
    a1 = __builtin_amdgcn_mfma_f32_16x16x32_bf16(av, bv[kc][1], a1, 0, 0, 0); \
    a2 = __builtin_amdgcn_mfma_f32_16x16x32_bf16(av, bv[kc][2], a2, 0, 0, 0); \
    a3 = __builtin_amdgcn_mfma_f32_16x16x32_bf16(av, bv[kc][3], a3, 0, 0, 0); \
    } while (0)

__global__ __launch_bounds__(WVS * 64, 2)
void dgemm9_kernel(const unsigned short* __restrict__ fsb,
                   const unsigned short* __restrict__ ftb,
                   const float* __restrict__ mem_s,
                   const float* __restrict__ mem_t,
                   short* __restrict__ DT0,      // bf16 [B][NDATA]
                   short* __restrict__ DT1)
{
    const int z = blockIdx.y;
    const unsigned short* fWb = z == 0 ? fsb : ftb;
    const float* mem          = z == 0 ? mem_t : mem_s;   // cross pairing
    short* DT                 = z == 0 ? DT0 : DT1;

    const int tid = threadIdx.x;
    const int w   = tid >> 6;          // wave 0..WVS-1
    const int l   = tid & 63;
    const int ln  = l & 15;
    const int ko  = l >> 4;            // 0..3
    const int xk  = ln & 7;            // read-side swizzle key
    const int wrowbase = blockIdx.x * ROWS_BLK + w * (TPW * 16);

    __shared__ __align__(16) float rows[WVS][3][16 * FEAT];  // 2 x 3 x 8 KB

    bf16x8 bv[4][4];
    #pragma unroll
    for (int kc = 0; kc < 4; ++kc)
        #pragma unroll
        for (int nt = 0; nt < 4; ++nt)
            bv[kc][nt] = *(const bf16x8*)(fWb + (nt * 16 + ln) * FEAT + kc * 32 + ko * 8);

#define STG(tt, bf) do { \
    _Pragma("unroll") \
    for (int p_ = 0; p_ < 8; ++p_) { \
        const int r_ = 2 * p_ + (l >> 5); \
        int gr_ = wrowbase + (tt) * 16 + r_; \
        if (gr_ >= NDATA) gr_ = NDATA - 1; \
        const float* g_ = mem + (size_t)gr_ * FEAT + (((l & 31) ^ (r_ & 7)) << 2); \
        GLL16(g_, &rows[w][bf][p_ * 256]); \
    } } while (0)

#define STORE_BF(cc, nt) do { \
    short4 s_; \
    s_.x = f2bf((cc).x); s_.y = f2bf((cc).y); \
    s_.z = f2bf((cc).z); s_.w = f2bf((cc).w); \
    *(short4*)(DT + (size_t)((nt) * 16 + ln) * NDATA + growb) = s_; \
    } while (0)

#define COMPUTE_STORE(t_, buf_) do { \
    const float* rb = &rows[w][buf_][ln * FEAT]; \
    f32x4 c0 = (f32x4){0.f,0.f,0.f,0.f}; \
    f32x4 c1 = (f32x4){0.f,0.f,0.f,0.f}; \
    f32x4 c2 = (f32x4){0.f,0.f,0.f,0.f}; \
    f32x4 c3 = (f32x4){0.f,0.f,0.f,0.f}; \
    _Pragma("unroll") \
    for (int kc = 0; kc < 4; ++kc) { \
        const int g0 = kc * 8 + ko * 2; \
        const float4 lo = *(const float4*)(rb + (((g0 + 0) ^ xk) << 2)); \
        const float4 hi = *(const float4*)(rb + (((g0 + 1) ^ xk) << 2)); \
        const bf16x8 av = (bf16x8){ f2bf(lo.x), f2bf(lo.y), f2bf(lo.z), f2bf(lo.w), \
                                    f2bf(hi.x), f2bf(hi.y), f2bf(hi.z), f2bf(hi.w) }; \
        MFMA4(av, kc, c0, c1, c2, c3); \
    } \
    const int growb = wrowbase + (t_) * 16 + ko * 4; \
    if (growb < NDATA) { \
        STORE_BF(c0, 0); \
        STORE_BF(c1, 1); \
        STORE_BF(c2, 2); \
        STORE_BF(c3, 3); \
    } } while (0)

    // prologue: two tiles in flight
    STG(0, 0);
    STG(1, 1);

    // t = 0
    asm volatile("s_waitcnt vmcnt(8)" ::: "memory");   // L0 done; L1 in flight
    __builtin_amdgcn_sched_barrier(0);
    COMPUTE_STORE(0, 0);
    STG(2, 2);

    // t = 1
    asm volatile("s_waitcnt vmcnt(12)" ::: "memory");  // L1 done; S0+L2 left
    __builtin_amdgcn_sched_barrier(0);
    COMPUTE_STORE(1, 1);
    STG(3, 0);

    // t = 2
    asm volatile("s_waitcnt vmcnt(12)" ::: "memory");  // L2 done; S1+L3 left
    __builtin_amdgcn_sched_barrier(0);
    COMPUTE_STORE(2, 2);

    // t = 3
    asm volatile("s_waitcnt vmcnt(4)" ::: "memory");   // L3 done; S2 left
    __builtin_amdgcn_sched_barrier(0);
    COMPUTE_STORE(3, 0);

#undef STG
#undef STORE_BF
#undef COMPUTE_STORE
}

// ---- K2b: out_raw + Ssum from bf16 DT ----
__global__ void gather2_kernel(const int* __restrict__ contrast_idx,
                               const unsigned short* __restrict__ DT0,
                               const unsigned short* __restrict__ DT1,
                               float* __restrict__ out_raw,  // [2][B*PK]
                               float* __restrict__ Ssum)     // [2]
{
    const int z   = blockIdx.z;
    const int b   = blockIdx.y;
    const int ks  = blockIdx.x;
    const int tid = threadIdx.x;
    const int k0  = ks * KSEG;
    const int kend = min(k0 + KSEG, PK);
    const float inv_t = 1.0f / 0.07f;
    const unsigned short* dtb = (z == 0 ? DT0 : DT1) + (size_t)b * NDATA;
    float* orz = out_raw + (size_t)z * (B * PK);
    float lsum = 0.0f;
    #pragma unroll 4
    for (int k = k0 + tid; k < kend; k += 256) {
        const int ci = contrast_idx[(size_t)b * PK + k];
        const float v = expf(bf2f(dtb[ci]) * inv_t);
        orz[(size_t)b * PK + k] = v;
        lsum += v;
    }
    __shared__ float red[256];
    red[tid] = lsum;
    __syncthreads();
    for (int s = 128; s > 0; s >>= 1) {
        if (tid < s) red[tid] += red[tid + s];
        __syncthreads();
    }
    if (tid == 0) atomicAdd(&Ssum[z], red[0]);
}

// ---- K3: weighted loss from out_raw ----
__global__ void ccd_loss_kernel(const float* __restrict__ out_raw,
                                const float* __restrict__ Ssum,
                                float* __restrict__ acc)
{
    const int z = blockIdx.y;
    const float S = Ssum[z];
    const float c = ((float)(B * PK)) / (S * (float)NDATA);

    const int total = B * PK;
    float contrib = 0.0f;
    for (int i = blockIdx.x * blockDim.x + threadIdx.x; i < total;
         i += gridDim.x * blockDim.x) {
        const float v = out_raw[(size_t)z * total + i] * c;
        const int k = i % PK;
        if (k < P) {
            contrib += logf(v / (v + M_PN + EPSC));
        } else {
            contrib += (float)P * logf(M_PN / (v + M_PN + EPSC));
        }
    }
    __shared__ float red[256];
    red[threadIdx.x] = contrib;
    __syncthreads();
    for (int s = 128; s > 0; s >>= 1) {
        if (threadIdx.x < s) red[threadIdx.x] += red[threadIdx.x + s];
        __syncthreads();
    }
    if (threadIdx.x == 0) atomicAdd(&acc[z], red[0]);
}

// ---------------- fallback K1 (R7): f = l2norm(f @ W + b) ----------------
__global__ void gemm_norm_kernel(const float* __restrict__ f_s,
                                 const float* __restrict__ f_t,
                                 const float* __restrict__ W_s,
                                 const float* __restrict__ b_s,
                                 const float* __restrict__ W_t,
                                 const float* __restrict__ b_t,
                                 float* __restrict__ out_fs,
                                 float* __restrict__ out_ft)
{
    const int row = blockIdx.x;
    const int z   = blockIdx.y;
    const float* f    = z == 0 ? f_s : f_t;
    const float* W    = z == 0 ? W_s : W_t;
    const float* bias = z == 0 ? b_s : b_t;
    float* out        = z == 0 ? out_fs : out_ft;

    __shared__ __align__(16) float frow[SDIM];
    const int t  = threadIdx.x;
    const int d  = t & 127;
    const int kh = t >> 7;
    for (int k = t; k < SDIM; k += 256) frow[k] = f[row * SDIM + k];
    __syncthreads();

    float acc = 0.0f;
    const int k0 = kh * (SDIM / 2);
    for (int k = k0; k < k0 + SDIM / 2; ++k)
        acc = fmaf(frow[k], W[k * FEAT + d], acc);

    __shared__ float part[2][128];
    part[kh][d] = acc;
    __syncthreads();
    const float a = part[0][d] + part[1][d] + bias[d];

    __shared__ float red[256];
    red[t] = (t < 128) ? a * a : 0.0f;
    __syncthreads();
    for (int s = 128; s > 0; s >>= 1) {
        if (t < s) red[t] += red[t + s];
        __syncthreads();
    }
    if (t < 128) out[row * FEAT + t] = a * (1.0f / sqrtf(red[0]));
}

// ---- FALLBACK dots (R7) ----
__global__ __launch_bounds__(64)
void dots_kernel(const float* __restrict__ fsn,
                 const float* __restrict__ ftn,
                 const int*   __restrict__ contrast_idx,
                 const float* __restrict__ mem_s,
                 const float* __restrict__ mem_t,
                 float* __restrict__ out_raw,
                 float* __restrict__ Ssum)
{
    const int z = blockIdx.z;
    const int b = blockIdx.y;
    const int l = threadIdx.x;
    const int kchunk = blockIdx.x * WCHUNK;

    const float* f   = (z == 0 ? fsn : ftn) + b * FEAT;
    const float* mem = (z == 0 ? mem_t : mem_s);

    __shared__ __align__(16) float rows[2][TILE * FEAT];
    __shared__ __align__(16) float fl[FEAT];
    __shared__ int cis[WCHUNK];

    fl[l]      = f[l];
    fl[l + 64] = f[l + 64];
    for (int i = l; i < WCHUNK; i += 64) {
        const int k = kchunk + i;
        cis[i] = contrast_idx[(size_t)b * PK + (k < PK ? k : PK - 1)];
    }
    __syncthreads();

    const int q   = l >> 4;
    const int r_c = l & 15;
    const int xk  = r_c & 7;
    const int rh  = l >> 5;
    const int sl  = l & 31;

    const float4* fg = (const float4*)fl;
    const float4 f0 = fg[q * 8 + 0], f1 = fg[q * 8 + 1];
    const float4 f2 = fg[q * 8 + 2], f3 = fg[q * 8 + 3];
    const float4 f4 = fg[q * 8 + 4], f5 = fg[q * 8 + 5];
    const float4 f6 = fg[q * 8 + 6], f7 = fg[q * 8 + 7];

    const float inv_t = 1.0f / 0.07f;
    const size_t obase = (size_t)z * (B * PK) + (size_t)b * PK;
    float lsum = 0.0f;

#define STAGE(tt, bf) do { \
    _Pragma("unroll") \
    for (int p_ = 0; p_ < 8; ++p_) { \
        const int rr_ = 2 * p_ + rh; \
        const int ci_ = cis[(tt) * TILE + rr_]; \
        const float* g_ = mem + (size_t)ci_ * FEAT + ((sl ^ (rr_ & 7)) << 2); \
        GLL16(g_, &rows[bf][p_ * 256]); \
    } } while (0)

    STAGE(0, 0);
    int cur = 0;
    for (int t = 0; t < NT; ++t) {
        if (t + 1 < NT) {
            STAGE(t + 1, cur ^ 1);
            asm volatile("s_waitcnt vmcnt(8)" ::: "memory");
        } else {
            asm volatile("s_waitcnt vmcnt(0)" ::: "memory");
        }
        __builtin_amdgcn_sched_barrier(0);

        const float* rbase = &rows[cur][r_c * FEAT];
        float dot;
        {
            const float4 m0 = *(const float4*)(rbase + (((q * 8 + 0) ^ xk) << 2));
            const float4 m1 = *(const float4*)(rbase + (((q * 8 + 1) ^ xk) << 2));
            const float4 m2 = *(const float4*)(rbase + (((q * 8 + 2) ^ xk) << 2));
            const float4 m3 = *(const float4*)(rbase + (((q * 8 + 3) ^ xk) << 2));
            const float4 m4 = *(const float4*)(rbase + (((q * 8 + 4) ^ xk) << 2));
            const float4 m5 = *(const float4*)(rbase + (((q * 8 + 5) ^ xk) << 2));
            const float4 m6 = *(const float4*)(rbase + (((q * 8 + 6) ^ xk) << 2));
            const float4 m7 = *(const float4*)(rbase + (((q * 8 + 7) ^ xk) << 2));
            dot = m0.x * f0.x;
            dot = fmaf(m0.y, f0.y, dot); dot = fmaf(m0.z, f0.z, dot); dot = fmaf(m0.w, f0.w, dot);
            dot = fmaf(m1.x, f1.x, dot); dot = fmaf(m1.y, f1.y, dot); dot = fmaf(m1.z, f1.z, dot); dot = fmaf(m1.w, f1.w, dot);
            dot = fmaf(m2.x, f2.x, dot); dot = fmaf(m2.y, f2.y, dot); dot = fmaf(m2.z, f2.z, dot); dot = fmaf(m2.w, f2.w, dot);
            dot = fmaf(m3.x, f3.x, dot); dot = fmaf(m3.y, f3.y, dot); dot = fmaf(m3.z, f3.z, dot); dot = fmaf(m3.w, f3.w, dot);
            dot = fmaf(m4.x, f4.x, dot); dot = fmaf(m4.y, f4.y, dot); dot = fmaf(m4.z, f4.z, dot); dot = fmaf(m4.w, f4.w, dot);
            dot = fmaf(m5.x, f5.x, dot); dot = fmaf(m5.y, f5.y, dot); dot = fmaf(m5.z, f5.z, dot); dot = fmaf(m5.w, f5.w, dot);
            dot = fmaf(m6.x, f6.x, dot); dot = fmaf(m6.y, f6.y, dot); dot = fmaf(m6.z, f6.z, dot); dot = fmaf(m6.w, f6.w, dot);
            dot = fmaf(m7.x, f7.x, dot); dot = fmaf(m7.y, f7.y, dot); dot = fmaf(m7.z, f7.z, dot); dot = fmaf(m7.w, f7.w, dot);
        }
        dot += __shfl_xor(dot, 16);
        dot += __shfl_xor(dot, 32);

        const int krow = kchunk + t * TILE + r_c;
        if (q == 0 && krow < PK) {
            const float val = expf(dot * inv_t);
            out_raw[obase + krow] = val;
            lsum += val;
        }
        cur ^= 1;
    }
#undef STAGE

    lsum += __shfl_xor(lsum, 8);
    lsum += __shfl_xor(lsum, 4);
    lsum += __shfl_xor(lsum, 2);
    lsum += __shfl_xor(lsum, 1);
    if (l == 0) atomicAdd(&Ssum[z], lsum);
}

// ---- fallback-only standalone upd ----
__global__ void upd_kernel(const float* __restrict__ fsn,
                           const float* __restrict__ ftn,
                           const int*   __restrict__ idx,
                           const float* __restrict__ mem_s,
                           const float* __restrict__ mem_t,
                           float* __restrict__ upd)
{
    const int z = blockIdx.y;
    const int b = blockIdx.x;
    const int d = threadIdx.x;
    const float* mem = z == 0 ? mem_s : mem_t;
    const float* f   = z == 0 ? fsn : ftn;
    const int i = idx[b];
    const float v = mem[(size_t)i * FEAT + d] * 0.5f + f[b * FEAT + d] * 0.5f;
    __shared__ float red[128];
    red[d] = v * v;
    __syncthreads();
    for (int s = 64; s > 0; s >>= 1) {
        if (d < s) red[d] += red[d + s];
        __syncthreads();
    }
    upd[(size_t)z * (B * FEAT) + b * FEAT + d] = v * (1.0f / sqrtf(red[0]));
}

// ---- K5: anchors partial with INLINE remap ----
__global__ void anchors_partial2_kernel(const int* __restrict__ class_index,
                                        const int* __restrict__ idx,
                                        const float* __restrict__ mem_s,
                                        const float* __restrict__ mem_t,
                                        const float* __restrict__ upd,
                                        float* __restrict__ partial)
{
    const int z     = blockIdx.z;
    const int c     = blockIdx.y;
    const int chunk = blockIdx.x;
    const int d     = threadIdx.x;     // 128
    const float* mem = z == 0 ? mem_s : mem_t;
    const float* u   = upd + (size_t)z * (B * FEAT);

    __shared__ int lidx[B];
    __shared__ int cis[CS];
    __shared__ int rbs[CS];
    if (d < B) lidx[d] = idx[d];
    __syncthreads();
    if (d < CS) {
        const int e = c * PER + chunk * CS + d;
        const int ci = class_index[e];
        int rb = -1;
        for (int b = B - 1; b >= 0; --b) {
            if (lidx[b] == ci) { rb = b; break; }
        }
        cis[d] = ci;
        rbs[d] = rb;
    }
    __syncthreads();

    float acc = 0.0f;
    #pragma unroll 4
    for (int j = 0; j < CS; ++j) {
        const int ci = cis[j];
        const int rb = rbs[j];
        const float* row = (rb >= 0) ? (u + rb * FEAT) : (mem + (size_t)ci * FEAT);
        const float v = row[d];
        acc += v > 0.0f ? v : 0.0f;
    }
    atomicAdd(&partial[(size_t)z * (NCLS * FEAT) + c * FEAT + d], acc);
}

// ---- K6 v2: anchors-finish + relation loss + final assembly (fused) ----
__global__ void final2_kernel(const float* __restrict__ fsn,
                              const float* __restrict__ ftn,
                              const float* __restrict__ partial,  // [2][NCLS][FEAT]
                              const float* __restrict__ acc,
                              float* __restrict__ d_out)
{
    __shared__ float an[2 * NCLS * FEAT];
    __shared__ float red[128];
    const int tid = threadIdx.x;            // 128

    for (int zc = 0; zc < 2 * NCLS; ++zc) {
        const float mv = partial[(size_t)zc * FEAT + tid] * (1.0f / (float)PER);
        red[tid] = mv * mv;
        __syncthreads();
        for (int s = 64; s > 0; s >>= 1) {
            if (tid < s) red[tid] += red[tid + s];
            __syncthreads();
        }
        an[zc * FEAT + tid] = mv * (1.0f / sqrtf(red[0]));
        __syncthreads();
    }

    float contrib = 0.0f;
    if (tid < 64) {
        const int b = tid;
        const float* sa = an;
        const float* ta = an + NCLS * FEAT;
        float srel[NCLS], trel[NCLS];
        for (int j = 0; j < NCLS; ++j) { srel[j] = 0.0f; trel[j] = 0.0f; }
        for (int d = 0; d < FEAT; ++d) {
            const float fs = fsn[b * FEAT + d];
            const float ft = ftn[b * FEAT + d];
            #pragma unroll
            for (int j = 0; j < NCLS; ++j) {
                srel[j] = fmaf(fs, sa[j * FEAT + d], srel[j]);
                trel[j] = fmaf(ft, ta[j * FEAT + d], trel[j]);
            }
        }
        const float inv_t = 1.0f / 0.07f;
        float smax = -1e30f, tmax = -1e30f;
        for (int j = 0; j < NCLS; ++j) {
            srel[j] *= inv_t; trel[j] *= inv_t;
            smax = fmaxf(smax, srel[j]);
            tmax = fmaxf(tmax, trel[j]);
        }
        float ssum = 0.0f, tsum = 0.0f;
        float texp[NCLS];
        for (int j = 0; j < NCLS; ++j) {
            ssum += expf(srel[j] - smax);
            texp[j] = expf(trel[j] - tmax);
            tsum += texp[j];
        }
        const float lse_s = logf(ssum);
        for (int j = 0; j < NCLS; ++j) {
            const float tgt = texp[j] / tsum;
            const float log_in = srel[j] - smax - lse_s;
            contrib += tgt * (logf(tgt + 1e-30f) - log_in);
        }
        for (int off = 32; off > 0; off >>= 1) contrib += __shfl_down(contrib, off);
        if (tid == 0) {
            d_out[1] = contrib / (float)B;
            d_out[0] = -(acc[0] + acc[1]) / (float)(B * P);
        }
    }
}

extern "C" void kernel_launch(void* const* d_in, const int* in_sizes, int n_in,
                              void* d_out_v, int out_size, void* d_ws, size_t ws_size,
                              hipStream_t stream)
{
    const float* f_s = (const float*)d_in[0];
    const float* f_t = (const float*)d_in[1];
    const int*   idx = (const int*)d_in[2];
    const int*   class_index = (const int*)d_in[4];
    const int*   contrast_idx = (const int*)d_in[6];
    const float* W_s = (const float*)d_in[7];
    const float* b_s = (const float*)d_in[8];
    const float* W_t = (const float*)d_in[9];
    const float* b_t = (const float*)d_in[10];
    const float* mem_s = (const float*)d_in[11];
    const float* mem_t = (const float*)d_in[12];

    float* out    = (float*)d_out_v;
    float* out_fs = out + 2;
    float* out_ft = out + 2 + B * FEAT;

    float* ws = (float*)d_ws;
    const size_t fl = ws_size / sizeof(float);
    const size_t REST = 2 * (size_t)B * PK   /* out_raw */
                      + (size_t)B * FEAT     /* fsb+ftb (bf16) */
                      + (size_t)KS1 * 2 * B * FEAT  /* fbp */
                      + 2 * B * FEAT         /* upd      */
                      + 2 * NCLS * FEAT      /* partial  */
                      + 64;
    const bool fit = fl >= 2 * DTBF + REST;  /* both bf16 tables */

    if (fit) {
        // ---------- bf16 D-table path, single dgemm launch ----------
        short* DT0 = (short*)ws;
        short* DT1 = (short*)(ws + DTBF);
        float* p   = ws + 2 * DTBF;
        float* out_raw = p;            p += 2 * (size_t)B * PK;
        unsigned short* fsb = (unsigned short*)p;  p += B * FEAT / 2;
        unsigned short* ftb = (unsigned short*)p;  p += B * FEAT / 2;
        float* fbp     = p;            p += (size_t)KS1 * 2 * B * FEAT;
        float* upd     = p;            p += 2 * B * FEAT;
        float* partial = p;            p += 2 * NCLS * FEAT;
        float* Ssum    = p;            p += 2;
        float* acc     = p;            p += 2;

        hipMemsetAsync(partial, 0, (2 * NCLS * FEAT + 4) * sizeof(float), stream);

        dim3 g1a(B, 2, KS1);
        gemm_partial_kernel<<<g1a, 256, 0, stream>>>(f_s, f_t, W_s, W_t, fbp);
        dim3 g1b(B, 2);
        norm_finish_kernel<<<g1b, 128, 0, stream>>>(fbp, b_s, b_t, idx,
                                                    mem_s, mem_t,
                                                    out_fs, out_ft, fsb, ftb, upd);

        const int gblocks = (NDATA + ROWS_BLK - 1) / ROWS_BLK;   // 782
        dim3 gd(gblocks, 2);
        dgemm9_kernel<<<gd, WVS * 64, 0, stream>>>(fsb, ftb, mem_s, mem_t,
                                                   DT0, DT1);
        dim3 gg(KSPLIT, B, 2);
        gather2_kernel<<<gg, 256, 0, stream>>>(contrast_idx,
                                               (const unsigned short*)DT0,
                                               (const unsigned short*)DT1,
                                               out_raw, Ssum);

        dim3 g3(256, 2);
        ccd_loss_kernel<<<g3, 256, 0, stream>>>(out_raw, Ssum, acc);
        dim3 g5a(JCHUNKS, NCLS, 2);
        anchors_partial2_kernel<<<g5a, 128, 0, stream>>>(class_index, idx,
                                                         mem_s, mem_t, upd, partial);
        final2_kernel<<<1, 128, 0, stream>>>(out_fs, out_ft, partial, acc, out);
    } else {
        // ---------- fallback: R7-style path ----------
        float* out_raw = ws;
        float* upd     = out_raw + 2 * (B * PK);
        float* partial = upd + 2 * (B * FEAT);
        float* Ssum    = partial + 2 * (NCLS * FEAT);
        float* acc     = Ssum + 2;

        hipMemsetAsync(partial, 0, (2 * NCLS * FEAT + 4) * sizeof(float), stream);

        dim3 g1(B, 2);
        gemm_norm_kernel<<<g1, 256, 0, stream>>>(f_s, f_t, W_s, b_s, W_t, b_t,
                                                 out_fs, out_ft);
        dim3 g2((PK + WCHUNK - 1) / WCHUNK, B, 2);
        dots_kernel<<<g2, 64, 0, stream>>>(out_fs, out_ft, contrast_idx,
                                           mem_s, mem_t, out_raw, Ssum);
        dim3 g3(256, 2);
        ccd_loss_kernel<<<g3, 256, 0, stream>>>(out_raw, Ssum, acc);
        dim3 g4(B, 2);
        upd_kernel<<<g4, 128, 0, stream>>>(out_fs, out_ft, idx, mem_s, mem_t, upd);
        dim3 g5a(JCHUNKS, NCLS, 2);
        anchors_partial2_kernel<<<g5a, 128, 0, stream>>>(class_index, idx,
                                                         mem_s, mem_t, upd, partial);
        final2_kernel<<<1, 128, 0, stream>>>(out_fs, out_ft, partial, acc, out);
    }
}

// Round 21
// 111.326 us; speedup vs baseline: 1.0393x; 1.0211x over previous
//
#include <hip/hip_runtime.h>
#include <math.h>
#include <stdint.h>

#define B 64
#define SDIM 2048
#define FEAT 128
#define P 4
#define PK 8196
#define NCLS 7
#define PER 1000
#define NDATA 100000
#define EPSC 1e-7f
#define M_PN 0.08192f   /* (PK-P)/NDATA = 8192/100000 */
#define JCHUNKS 50
#define CS (PER / JCHUNKS)   /* 20 rows per block */

#define DTBF ((size_t)B * NDATA / 2)  /* float-units of one bf16 DT table */
#define KSPLIT 4
#define KSEG 2049            /* 4*2049 = 8196 = PK */
#define KS1 8                /* K-split for gemm_partial */
#define TPW 2                /* tiles (16 rows) per (single) wave */
#define ROWS_BLK (TPW * 16)  /* 32 rows per block */

/* fallback (R7) dots config */
#define TILE 16
#define WCHUNK 512
#define NT (WCHUNK / TILE)

#define GLL16(gp, lp) \
    __builtin_amdgcn_global_load_lds( \
        (__attribute__((address_space(1))) void*)(uintptr_t)(gp), \
        (__attribute__((address_space(3))) void*)(lp), 16, 0, 0)

typedef __attribute__((ext_vector_type(8))) short bf16x8;
typedef __attribute__((ext_vector_type(4))) float f32x4;

static __device__ __forceinline__ short f2bf(float x)
{
    union { float f; uint32_t u; } v; v.f = x;
    const uint32_t r = (v.u + 0x7fffu + ((v.u >> 16) & 1u)) >> 16;
    return (short)r;
}
static __device__ __forceinline__ float bf2f(unsigned short u)
{
    union { uint32_t u; float f; } v; v.u = ((uint32_t)u) << 16;
    return v.f;
}

// ---- K1a: fbp[ks][z][row][d] = partial dot over one K-chunk (no atomics) ----
__global__ void gemm_partial_kernel(const float* __restrict__ f_s,
                                    const float* __restrict__ f_t,
                                    const float* __restrict__ W_s,
                                    const float* __restrict__ W_t,
                                    float* __restrict__ fbp)  // [KS1][2][B][FEAT]
{
    const int row = blockIdx.x;
    const int z   = blockIdx.y;
    const int ks  = blockIdx.z;        // 0..KS1-1
    const float* f = z == 0 ? f_s : f_t;
    const float* W = z == 0 ? W_s : W_t;

    const int t  = threadIdx.x;        // 0..255
    const int d  = t & 127;
    const int kh = t >> 7;             // 0/1

    __shared__ float frow[SDIM / KS1]; // 256
    frow[t] = f[row * SDIM + ks * (SDIM / KS1) + t];
    __syncthreads();

    float acc = 0.0f;
    const int kb = ks * (SDIM / KS1) + kh * 128;
    #pragma unroll 8
    for (int k = 0; k < 128; ++k)
        acc = fmaf(frow[kh * 128 + k], W[(kb + k) * FEAT + d], acc);

    __shared__ float part[2][128];
    part[kh][d] = acc;
    __syncthreads();
    if (t < 128)
        fbp[(((size_t)ks * 2 + z) * B + row) * FEAT + t] = part[0][t] + part[1][t];
}

// ---- K1b: sum ks-slices + bias + l2norm; ALSO computes upd (fused) ----
__global__ void norm_finish_kernel(const float* __restrict__ fbp,
                                   const float* __restrict__ b_s,
                                   const float* __restrict__ b_t,
                                   const int*   __restrict__ idx,
                                   const float* __restrict__ mem_s,
                                   const float* __restrict__ mem_t,
                                   float* __restrict__ out_fs,
                                   float* __restrict__ out_ft,
                                   unsigned short* __restrict__ fsb,
                                   unsigned short* __restrict__ ftb,
                                   float* __restrict__ upd)   // [2][B][FEAT]
{
    const int row = blockIdx.x;
    const int z   = blockIdx.y;
    const int d   = threadIdx.x;       // 128
    const float* bias = z == 0 ? b_s : b_t;
    float* out = z == 0 ? out_fs : out_ft;
    unsigned short* fbx = z == 0 ? fsb : ftb;

    float a = bias[d];
    #pragma unroll
    for (int ks = 0; ks < KS1; ++ks)
        a += fbp[(((size_t)ks * 2 + z) * B + row) * FEAT + d];

    __shared__ float red[128];
    red[d] = a * a;
    __syncthreads();
    for (int s = 64; s > 0; s >>= 1) {
        if (d < s) red[d] += red[d + s];
        __syncthreads();
    }
    const float v = a * (1.0f / sqrtf(red[0]));
    out[row * FEAT + d] = v;
    fbx[row * FEAT + d] = (unsigned short)f2bf(v);
    __syncthreads();                   // red reuse

    const float* mem = z == 0 ? mem_s : mem_t;   // NOT cross-paired here
    const int i = idx[row];
    const float u = mem[(size_t)i * FEAT + d] * 0.5f + v * 0.5f;
    red[d] = u * u;
    __syncthreads();
    for (int s = 64; s > 0; s >>= 1) {
        if (d < s) red[d] += red[d + s];
        __syncthreads();
    }
    upd[((size_t)z * B + row) * FEAT + d] = u * (1.0f / sqrtf(red[0]));
}

// ---- K2a v10: DT(bf16) = mem . f; 1-WAVE blocks, 2 tiles, 16 KB LDS ----
// Discriminator probe: if the ~2.5-3 TB/s ceiling is a per-WAVE DMA limit,
// 10 resident 1-wave blocks/CU (LDS-capped), each issuing all 16 KB of its
// loads in the prologue, multiplies in-flight bytes by block churn. If the
// limit is per-CU, this is null and the roofline is declared.
#define MFMA4(av, kc, a0, a1, a2, a3) do { \
    a0 = __builtin_amdgcn_mfma_f32_16x16x32_bf16(av, bv[kc][0], a0, 0, 0, 0); \
    a1 = __builtin_amdgcn_mfma_f32_16x16x32_bf16(av, bv[kc][1], a1, 0, 0, 0); \
    a2 = __builtin_amdgcn_mfma_f32_16x16x32_bf16(av, bv[kc][2], a2, 0, 0, 0); \
    a3 = __builtin_amdgcn_mfma_f32_16x16x32_bf16(av, bv[kc][3], a3, 0, 0, 0); \
    } while (0)

__global__ __launch_bounds__(64)
void dgemm10_kernel(const unsigned short* __restrict__ fsb,
                    const unsigned short* __restrict__ ftb,
                    const float* __restrict__ mem_s,
                    const float* __restrict__ mem_t,
                    short* __restrict__ DT0,      // bf16 [B][NDATA]
                    short* __restrict__ DT1)
{
    const int z = blockIdx.y;
    const unsigned short* fWb = z == 0 ? fsb : ftb;
    const float* mem          = z == 0 ? mem_t : mem_s;   // cross pairing
    short* DT                 = z == 0 ? DT0 : DT1;

    const int l   = threadIdx.x;       // 0..63
    const int ln  = l & 15;
    const int ko  = l >> 4;            // 0..3
    const int xk  = ln & 7;            // read-side swizzle key
    const int wrowbase = blockIdx.x * ROWS_BLK;

    __shared__ __align__(16) float rows[2][16 * FEAT];  // 2 x 8 KB

#define STG(tt, bf) do { \
    _Pragma("unroll") \
    for (int p_ = 0; p_ < 8; ++p_) { \
        const int r_ = 2 * p_ + (l >> 5); \
        int gr_ = wrowbase + (tt) * 16 + r_; \
        if (gr_ >= NDATA) gr_ = NDATA - 1; \
        const float* g_ = mem + (size_t)gr_ * FEAT + (((l & 31) ^ (r_ & 7)) << 2); \
        GLL16(g_, &rows[bf][p_ * 256]); \
    } } while (0)

#define STORE_BF(cc, nt) do { \
    short4 s_; \
    s_.x = f2bf((cc).x); s_.y = f2bf((cc).y); \
    s_.z = f2bf((cc).z); s_.w = f2bf((cc).w); \
    *(short4*)(DT + (size_t)((nt) * 16 + ln) * NDATA + growb) = s_; \
    } while (0)

#define COMPUTE_STORE(t_, buf_) do { \
    const float* rb = &rows[buf_][ln * FEAT]; \
    f32x4 c0 = (f32x4){0.f,0.f,0.f,0.f}; \
    f32x4 c1 = (f32x4){0.f,0.f,0.f,0.f}; \
    f32x4 c2 = (f32x4){0.f,0.f,0.f,0.f}; \
    f32x4 c3 = (f32x4){0.f,0.f,0.f,0.f}; \
    _Pragma("unroll") \
    for (int kc = 0; kc < 4; ++kc) { \
        const int g0 = kc * 8 + ko * 2; \
        const float4 lo = *(const float4*)(rb + (((g0 + 0) ^ xk) << 2)); \
        const float4 hi = *(const float4*)(rb + (((g0 + 1) ^ xk) << 2)); \
        const bf16x8 av = (bf16x8){ f2bf(lo.x), f2bf(lo.y), f2bf(lo.z), f2bf(lo.w), \
                                    f2bf(hi.x), f2bf(hi.y), f2bf(hi.z), f2bf(hi.w) }; \
        MFMA4(av, kc, c0, c1, c2, c3); \
    } \
    const int growb = wrowbase + (t_) * 16 + ko * 4; \
    if (growb < NDATA) { \
        STORE_BF(c0, 0); \
        STORE_BF(c1, 1); \
        STORE_BF(c2, 2); \
        STORE_BF(c3, 3); \
    } } while (0)

    // prologue: the block's ENTIRE load set (16 KB) goes out immediately
    STG(0, 0);
    STG(1, 1);

    // bv loads after the LDS DMA is queued (L1/L2-hot table)
    bf16x8 bv[4][4];
    #pragma unroll
    for (int kc = 0; kc < 4; ++kc)
        #pragma unroll
        for (int nt = 0; nt < 4; ++nt)
            bv[kc][nt] = *(const bf16x8*)(fWb + (nt * 16 + ln) * FEAT + kc * 32 + ko * 8);

    // t = 0: outstanding L0(8), L1(8), bv(16 VGPR loads — counted too).
    // bv loads must complete before MFMA anyway; wait for L0 + bv,
    // leave L1 in flight: vmcnt(8).
    asm volatile("s_waitcnt vmcnt(8)" ::: "memory");
    __builtin_amdgcn_sched_barrier(0);
    COMPUTE_STORE(0, 0);

    // t = 1: outstanding L1(8), S0(4); want L1 done -> leave 4.
    asm volatile("s_waitcnt vmcnt(4)" ::: "memory");
    __builtin_amdgcn_sched_barrier(0);
    COMPUTE_STORE(1, 1);

#undef STG
#undef STORE_BF
#undef COMPUTE_STORE
}

// ---- K2b: out_raw + Ssum from bf16 DT ----
__global__ void gather2_kernel(const int* __restrict__ contrast_idx,
                               const unsigned short* __restrict__ DT0,
                               const unsigned short* __restrict__ DT1,
                               float* __restrict__ out_raw,  // [2][B*PK]
                               float* __restrict__ Ssum)     // [2]
{
    const int z   = blockIdx.z;
    const int b   = blockIdx.y;
    const int ks  = blockIdx.x;
    const int tid = threadIdx.x;
    const int k0  = ks * KSEG;
    const int kend = min(k0 + KSEG, PK);
    const float inv_t = 1.0f / 0.07f;
    const unsigned short* dtb = (z == 0 ? DT0 : DT1) + (size_t)b * NDATA;
    float* orz = out_raw + (size_t)z * (B * PK);
    float lsum = 0.0f;
    #pragma unroll 4
    for (int k = k0 + tid; k < kend; k += 256) {
        const int ci = contrast_idx[(size_t)b * PK + k];
        const float v = expf(bf2f(dtb[ci]) * inv_t);
        orz[(size_t)b * PK + k] = v;
        lsum += v;
    }
    __shared__ float red[256];
    red[tid] = lsum;
    __syncthreads();
    for (int s = 128; s > 0; s >>= 1) {
        if (tid < s) red[tid] += red[tid + s];
        __syncthreads();
    }
    if (tid == 0) atomicAdd(&Ssum[z], red[0]);
}

// ---- K3: weighted loss from out_raw ----
__global__ void ccd_loss_kernel(const float* __restrict__ out_raw,
                                const float* __restrict__ Ssum,
                                float* __restrict__ acc)
{
    const int z = blockIdx.y;
    const float S = Ssum[z];
    const float c = ((float)(B * PK)) / (S * (float)NDATA);

    const int total = B * PK;
    float contrib = 0.0f;
    for (int i = blockIdx.x * blockDim.x + threadIdx.x; i < total;
         i += gridDim.x * blockDim.x) {
        const float v = out_raw[(size_t)z * total + i] * c;
        const int k = i % PK;
        if (k < P) {
            contrib += logf(v / (v + M_PN + EPSC));
        } else {
            contrib += (float)P * logf(M_PN / (v + M_PN + EPSC));
        }
    }
    __shared__ float red[256];
    red[threadIdx.x] = contrib;
    __syncthreads();
    for (int s = 128; s > 0; s >>= 1) {
        if (threadIdx.x < s) red[threadIdx.x] += red[threadIdx.x + s];
        __syncthreads();
    }
    if (threadIdx.x == 0) atomicAdd(&acc[z], red[0]);
}

// ---------------- fallback K1 (R7): f = l2norm(f @ W + b) ----------------
__global__ void gemm_norm_kernel(const float* __restrict__ f_s,
                                 const float* __restrict__ f_t,
                                 const float* __restrict__ W_s,
                                 const float* __restrict__ b_s,
                                 const float* __restrict__ W_t,
                                 const float* __restrict__ b_t,
                                 float* __restrict__ out_fs,
                                 float* __restrict__ out_ft)
{
    const int row = blockIdx.x;
    const int z   = blockIdx.y;
    const float* f    = z == 0 ? f_s : f_t;
    const float* W    = z == 0 ? W_s : W_t;
    const float* bias = z == 0 ? b_s : b_t;
    float* out        = z == 0 ? out_fs : out_ft;

    __shared__ __align__(16) float frow[SDIM];
    const int t  = threadIdx.x;
    const int d  = t & 127;
    const int kh = t >> 7;
    for (int k = t; k < SDIM; k += 256) frow[k] = f[row * SDIM + k];
    __syncthreads();

    float acc = 0.0f;
    const int k0 = kh * (SDIM / 2);
    for (int k = k0; k < k0 + SDIM / 2; ++k)
        acc = fmaf(frow[k], W[k * FEAT + d], acc);

    __shared__ float part[2][128];
    part[kh][d] = acc;
    __syncthreads();
    const float a = part[0][d] + part[1][d] + bias[d];

    __shared__ float red[256];
    red[t] = (t < 128) ? a * a : 0.0f;
    __syncthreads();
    for (int s = 128; s > 0; s >>= 1) {
        if (t < s) red[t] += red[t + s];
        __syncthreads();
    }
    if (t < 128) out[row * FEAT + t] = a * (1.0f / sqrtf(red[0]));
}

// ---- FALLBACK dots (R7) ----
__global__ __launch_bounds__(64)
void dots_kernel(const float* __restrict__ fsn,
                 const float* __restrict__ ftn,
                 const int*   __restrict__ contrast_idx,
                 const float* __restrict__ mem_s,
                 const float* __restrict__ mem_t,
                 float* __restrict__ out_raw,
                 float* __restrict__ Ssum)
{
    const int z = blockIdx.z;
    const int b = blockIdx.y;
    const int l = threadIdx.x;
    const int kchunk = blockIdx.x * WCHUNK;

    const float* f   = (z == 0 ? fsn : ftn) + b * FEAT;
    const float* mem = (z == 0 ? mem_t : mem_s);

    __shared__ __align__(16) float rows[2][TILE * FEAT];
    __shared__ __align__(16) float fl[FEAT];
    __shared__ int cis[WCHUNK];

    fl[l]      = f[l];
    fl[l + 64] = f[l + 64];
    for (int i = l; i < WCHUNK; i += 64) {
        const int k = kchunk + i;
        cis[i] = contrast_idx[(size_t)b * PK + (k < PK ? k : PK - 1)];
    }
    __syncthreads();

    const int q   = l >> 4;
    const int r_c = l & 15;
    const int xk  = r_c & 7;
    const int rh  = l >> 5;
    const int sl  = l & 31;

    const float4* fg = (const float4*)fl;
    const float4 f0 = fg[q * 8 + 0], f1 = fg[q * 8 + 1];
    const float4 f2 = fg[q * 8 + 2], f3 = fg[q * 8 + 3];
    const float4 f4 = fg[q * 8 + 4], f5 = fg[q * 8 + 5];
    const float4 f6 = fg[q * 8 + 6], f7 = fg[q * 8 + 7];

    const float inv_t = 1.0f / 0.07f;
    const size_t obase = (size_t)z * (B * PK) + (size_t)b * PK;
    float lsum = 0.0f;

#define STAGE(tt, bf) do { \
    _Pragma("unroll") \
    for (int p_ = 0; p_ < 8; ++p_) { \
        const int rr_ = 2 * p_ + rh; \
        const int ci_ = cis[(tt) * TILE + rr_]; \
        const float* g_ = mem + (size_t)ci_ * FEAT + ((sl ^ (rr_ & 7)) << 2); \
        GLL16(g_, &rows[bf][p_ * 256]); \
    } } while (0)

    STAGE(0, 0);
    int cur = 0;
    for (int t = 0; t < NT; ++t) {
        if (t + 1 < NT) {
            STAGE(t + 1, cur ^ 1);
            asm volatile("s_waitcnt vmcnt(8)" ::: "memory");
        } else {
            asm volatile("s_waitcnt vmcnt(0)" ::: "memory");
        }
        __builtin_amdgcn_sched_barrier(0);

        const float* rbase = &rows[cur][r_c * FEAT];
        float dot;
        {
            const float4 m0 = *(const float4*)(rbase + (((q * 8 + 0) ^ xk) << 2));
            const float4 m1 = *(const float4*)(rbase + (((q * 8 + 1) ^ xk) << 2));
            const float4 m2 = *(const float4*)(rbase + (((q * 8 + 2) ^ xk) << 2));
            const float4 m3 = *(const float4*)(rbase + (((q * 8 + 3) ^ xk) << 2));
            const float4 m4 = *(const float4*)(rbase + (((q * 8 + 4) ^ xk) << 2));
            const float4 m5 = *(const float4*)(rbase + (((q * 8 + 5) ^ xk) << 2));
            const float4 m6 = *(const float4*)(rbase + (((q * 8 + 6) ^ xk) << 2));
            const float4 m7 = *(const float4*)(rbase + (((q * 8 + 7) ^ xk) << 2));
            dot = m0.x * f0.x;
            dot = fmaf(m0.y, f0.y, dot); dot = fmaf(m0.z, f0.z, dot); dot = fmaf(m0.w, f0.w, dot);
            dot = fmaf(m1.x, f1.x, dot); dot = fmaf(m1.y, f1.y, dot); dot = fmaf(m1.z, f1.z, dot); dot = fmaf(m1.w, f1.w, dot);
            dot = fmaf(m2.x, f2.x, dot); dot = fmaf(m2.y, f2.y, dot); dot = fmaf(m2.z, f2.z, dot); dot = fmaf(m2.w, f2.w, dot);
            dot = fmaf(m3.x, f3.x, dot); dot = fmaf(m3.y, f3.y, dot); dot = fmaf(m3.z, f3.z, dot); dot = fmaf(m3.w, f3.w, dot);
            dot = fmaf(m4.x, f4.x, dot); dot = fmaf(m4.y, f4.y, dot); dot = fmaf(m4.z, f4.z, dot); dot = fmaf(m4.w, f4.w, dot);
            dot = fmaf(m5.x, f5.x, dot); dot = fmaf(m5.y, f5.y, dot); dot = fmaf(m5.z, f5.z, dot); dot = fmaf(m5.w, f5.w, dot);
            dot = fmaf(m6.x, f6.x, dot); dot = fmaf(m6.y, f6.y, dot); dot = fmaf(m6.z, f6.z, dot); dot = fmaf(m6.w, f6.w, dot);
            dot = fmaf(m7.x, f7.x, dot); dot = fmaf(m7.y, f7.y, dot); dot = fmaf(m7.z, f7.z, dot); dot = fmaf(m7.w, f7.w, dot);
        }
        dot += __shfl_xor(dot, 16);
        dot += __shfl_xor(dot, 32);

        const int krow = kchunk + t * TILE + r_c;
        if (q == 0 && krow < PK) {
            const float val = expf(dot * inv_t);
            out_raw[obase + krow] = val;
            lsum += val;
        }
        cur ^= 1;
    }
#undef STAGE

    lsum += __shfl_xor(lsum, 8);
    lsum += __shfl_xor(lsum, 4);
    lsum += __shfl_xor(lsum, 2);
    lsum += __shfl_xor(lsum, 1);
    if (l == 0) atomicAdd(&Ssum[z], lsum);
}

// ---- fallback-only standalone upd ----
__global__ void upd_kernel(const float* __restrict__ fsn,
                           const float* __restrict__ ftn,
                           const int*   __restrict__ idx,
                           const float* __restrict__ mem_s,
                           const float* __restrict__ mem_t,
                           float* __restrict__ upd)
{
    const int z = blockIdx.y;
    const int b = blockIdx.x;
    const int d = threadIdx.x;
    const float* mem = z == 0 ? mem_s : mem_t;
    const float* f   = z == 0 ? fsn : ftn;
    const int i = idx[b];
    const float v = mem[(size_t)i * FEAT + d] * 0.5f + f[b * FEAT + d] * 0.5f;
    __shared__ float red[128];
    red[d] = v * v;
    __syncthreads();
    for (int s = 64; s > 0; s >>= 1) {
        if (d < s) red[d] += red[d + s];
        __syncthreads();
    }
    upd[(size_t)z * (B * FEAT) + b * FEAT + d] = v * (1.0f / sqrtf(red[0]));
}

// ---- K5: anchors partial with INLINE remap ----
__global__ void anchors_partial2_kernel(const int* __restrict__ class_index,
                                        const int* __restrict__ idx,
                                        const float* __restrict__ mem_s,
                                        const float* __restrict__ mem_t,
                                        const float* __restrict__ upd,
                                        float* __restrict__ partial)
{
    const int z     = blockIdx.z;
    const int c     = blockIdx.y;
    const int chunk = blockIdx.x;
    const int d     = threadIdx.x;     // 128
    const float* mem = z == 0 ? mem_s : mem_t;
    const float* u   = upd + (size_t)z * (B * FEAT);

    __shared__ int lidx[B];
    __shared__ int cis[CS];
    __shared__ int rbs[CS];
    if (d < B) lidx[d] = idx[d];
    __syncthreads();
    if (d < CS) {
        const int e = c * PER + chunk * CS + d;
        const int ci = class_index[e];
        int rb = -1;
        for (int b = B - 1; b >= 0; --b) {
            if (lidx[b] == ci) { rb = b; break; }
        }
        cis[d] = ci;
        rbs[d] = rb;
    }
    __syncthreads();

    float acc = 0.0f;
    #pragma unroll 4
    for (int j = 0; j < CS; ++j) {
        const int ci = cis[j];
        const int rb = rbs[j];
        const float* row = (rb >= 0) ? (u + rb * FEAT) : (mem + (size_t)ci * FEAT);
        const float v = row[d];
        acc += v > 0.0f ? v : 0.0f;
    }
    atomicAdd(&partial[(size_t)z * (NCLS * FEAT) + c * FEAT + d], acc);
}

// ---- K6 v2: anchors-finish + relation loss + final assembly (fused) ----
__global__ void final2_kernel(const float* __restrict__ fsn,
                              const float* __restrict__ ftn,
                              const float* __restrict__ partial,  // [2][NCLS][FEAT]
                              const float* __restrict__ acc,
                              float* __restrict__ d_out)
{
    __shared__ float an[2 * NCLS * FEAT];
    __shared__ float red[128];
    const int tid = threadIdx.x;            // 128

    for (int zc = 0; zc < 2 * NCLS; ++zc) {
        const float mv = partial[(size_t)zc * FEAT + tid] * (1.0f / (float)PER);
        red[tid] = mv * mv;
        __syncthreads();
        for (int s = 64; s > 0; s >>= 1) {
            if (tid < s) red[tid] += red[tid + s];
            __syncthreads();
        }
        an[zc * FEAT + tid] = mv * (1.0f / sqrtf(red[0]));
        __syncthreads();
    }

    float contrib = 0.0f;
    if (tid < 64) {
        const int b = tid;
        const float* sa = an;
        const float* ta = an + NCLS * FEAT;
        float srel[NCLS], trel[NCLS];
        for (int j = 0; j < NCLS; ++j) { srel[j] = 0.0f; trel[j] = 0.0f; }
        for (int d = 0; d < FEAT; ++d) {
            const float fs = fsn[b * FEAT + d];
            const float ft = ftn[b * FEAT + d];
            #pragma unroll
            for (int j = 0; j < NCLS; ++j) {
                srel[j] = fmaf(fs, sa[j * FEAT + d], srel[j]);
                trel[j] = fmaf(ft, ta[j * FEAT + d], trel[j]);
            }
        }
        const float inv_t = 1.0f / 0.07f;
        float smax = -1e30f, tmax = -1e30f;
        for (int j = 0; j < NCLS; ++j) {
            srel[j] *= inv_t; trel[j] *= inv_t;
            smax = fmaxf(smax, srel[j]);
            tmax = fmaxf(tmax, trel[j]);
        }
        float ssum = 0.0f, tsum = 0.0f;
        float texp[NCLS];
        for (int j = 0; j < NCLS; ++j) {
            ssum += expf(srel[j] - smax);
            texp[j] = expf(trel[j] - tmax);
            tsum += texp[j];
        }
        const float lse_s = logf(ssum);
        for (int j = 0; j < NCLS; ++j) {
            const float tgt = texp[j] / tsum;
            const float log_in = srel[j] - smax - lse_s;
            contrib += tgt * (logf(tgt + 1e-30f) - log_in);
        }
        for (int off = 32; off > 0; off >>= 1) contrib += __shfl_down(contrib, off);
        if (tid == 0) {
            d_out[1] = contrib / (float)B;
            d_out[0] = -(acc[0] + acc[1]) / (float)(B * P);
        }
    }
}

extern "C" void kernel_launch(void* const* d_in, const int* in_sizes, int n_in,
                              void* d_out_v, int out_size, void* d_ws, size_t ws_size,
                              hipStream_t stream)
{
    const float* f_s = (const float*)d_in[0];
    const float* f_t = (const float*)d_in[1];
    const int*   idx = (const int*)d_in[2];
    const int*   class_index = (const int*)d_in[4];
    const int*   contrast_idx = (const int*)d_in[6];
    const float* W_s = (const float*)d_in[7];
    const float* b_s = (const float*)d_in[8];
    const float* W_t = (const float*)d_in[9];
    const float* b_t = (const float*)d_in[10];
    const float* mem_s = (const float*)d_in[11];
    const float* mem_t = (const float*)d_in[12];

    float* out    = (float*)d_out_v;
    float* out_fs = out + 2;
    float* out_ft = out + 2 + B * FEAT;

    float* ws = (float*)d_ws;
    const size_t fl = ws_size / sizeof(float);
    const size_t REST = 2 * (size_t)B * PK   /* out_raw */
                      + (size_t)B * FEAT     /* fsb+ftb (bf16) */
                      + (size_t)KS1 * 2 * B * FEAT  /* fbp */
                      + 2 * B * FEAT         /* upd      */
                      + 2 * NCLS * FEAT      /* partial  */
                      + 64;
    const bool fit = fl >= 2 * DTBF + REST;  /* both bf16 tables */

    if (fit) {
        // ---------- bf16 D-table path ----------
        short* DT0 = (short*)ws;
        short* DT1 = (short*)(ws + DTBF);
        float* p   = ws + 2 * DTBF;
        float* out_raw = p;            p += 2 * (size_t)B * PK;
        unsigned short* fsb = (unsigned short*)p;  p += B * FEAT / 2;
        unsigned short* ftb = (unsigned short*)p;  p += B * FEAT / 2;
        float* fbp     = p;            p += (size_t)KS1 * 2 * B * FEAT;
        float* upd     = p;            p += 2 * B * FEAT;
        float* partial = p;            p += 2 * NCLS * FEAT;
        float* Ssum    = p;            p += 2;
        float* acc     = p;            p += 2;

        hipMemsetAsync(partial, 0, (2 * NCLS * FEAT + 4) * sizeof(float), stream);

        dim3 g1a(B, 2, KS1);
        gemm_partial_kernel<<<g1a, 256, 0, stream>>>(f_s, f_t, W_s, W_t, fbp);
        dim3 g1b(B, 2);
        norm_finish_kernel<<<g1b, 128, 0, stream>>>(fbp, b_s, b_t, idx,
                                                    mem_s, mem_t,
                                                    out_fs, out_ft, fsb, ftb, upd);

        const int gblocks = (NDATA + ROWS_BLK - 1) / ROWS_BLK;   // 3125
        dim3 gd(gblocks, 2);
        dgemm10_kernel<<<gd, 64, 0, stream>>>(fsb, ftb, mem_s, mem_t,
                                              DT0, DT1);
        dim3 gg(KSPLIT, B, 2);
        gather2_kernel<<<gg, 256, 0, stream>>>(contrast_idx,
                                               (const unsigned short*)DT0,
                                               (const unsigned short*)DT1,
                                               out_raw, Ssum);

        dim3 g3(256, 2);
        ccd_loss_kernel<<<g3, 256, 0, stream>>>(out_raw, Ssum, acc);
        dim3 g5a(JCHUNKS, NCLS, 2);
        anchors_partial2_kernel<<<g5a, 128, 0, stream>>>(class_index, idx,
                                                         mem_s, mem_t, upd, partial);
        final2_kernel<<<1, 128, 0, stream>>>(out_fs, out_ft, partial, acc, out);
    } else {
        // ---------- fallback: R7-style path ----------
        float* out_raw = ws;
        float* upd     = out_raw + 2 * (B * PK);
        float* partial = upd + 2 * (B * FEAT);
        float* Ssum    = partial + 2 * (NCLS * FEAT);
        float* acc     = Ssum + 2;

        hipMemsetAsync(partial, 0, (2 * NCLS * FEAT + 4) * sizeof(float), stream);

        dim3 g1(B, 2);
        gemm_norm_kernel<<<g1, 256, 0, stream>>>(f_s, f_t, W_s, b_s, W_t, b_t,
                                                 out_fs, out_ft);
        dim3 g2((PK + WCHUNK - 1) / WCHUNK, B, 2);
        dots_kernel<<<g2, 64, 0, stream>>>(out_fs, out_ft, contrast_idx,
                                           mem_s, mem_t, out_raw, Ssum);
        dim3 g3(256, 2);
        ccd_loss_kernel<<<g3, 256, 0, stream>>>(out_raw, Ssum, acc);
        dim3 g4(B, 2);
        upd_kernel<<<g4, 128, 0, stream>>>(out_fs, out_ft, idx, mem_s, mem_t, upd);
        dim3 g5a(JCHUNKS, NCLS, 2);
        anchors_partial2_kernel<<<g5a, 128, 0, stream>>>(class_index, idx,
                                                         mem_s, mem_t, upd, partial);
        final2_kernel<<<1, 128, 0, stream>>>(out_fs, out_ft, partial, acc, out);
    }
}